// Round 5
// baseline (413.385 us; speedup 1.0000x reference)
//
#include <hip/hip_runtime.h>
#include <hip/hip_bf16.h>

#define N_FULL 262144
#define M_POOL 131072

typedef __attribute__((ext_vector_type(4))) float f32x4;
typedef __attribute__((ext_vector_type(8))) short bf16x8;
typedef __attribute__((ext_vector_type(8))) unsigned short u16x8;

static __device__ __forceinline__ unsigned short f2b(float f) {
    __hip_bfloat16 b = __float2bfloat16(f);
    return *reinterpret_cast<unsigned short*>(&b);
}
static __device__ __forceinline__ float b2f(unsigned short u) {
    unsigned int x = ((unsigned int)u) << 16;
    return __uint_as_float(x);
}

// async global->LDS, 16B per lane; LDS dest is wave-uniform base (HW adds lane*16)
static __device__ __forceinline__ void gll16(const void* g, void* l) {
    __builtin_amdgcn_global_load_lds(
        (const __attribute__((address_space(1))) void*)g,
        (__attribute__((address_space(3))) void*)l, 16, 0, 0);
}

// ---------- pack W2/W3 into MFMA B-fragment order, zero-padded to NPT taps ----------
// Wp[k][q][t][lane][j] = W[k][q*32 + (lane>>4)*8 + j][t*16 + (lane&15)], 0 for k>=27
template<int CT, int NPT>
__global__ __launch_bounds__(256) void pack_w_kernel(const float* __restrict__ W,
                                                     unsigned short* __restrict__ Wp) {
    int i = blockIdx.x * 256 + threadIdx.x;
    const int total = NPT * 2 * CT * 64 * 8;
    if (i >= total) return;
    int j = i & 7;
    int l = (i >> 3) & 63;
    int t = (i >> 9) % CT;
    int q = (i / (512 * CT)) & 1;
    int k = i / (1024 * CT);
    int cin = q * 32 + (l >> 4) * 8 + j;
    int cout = t * 16 + (l & 15);
    float v = (k < 27) ? W[(k * 64 + cin) * (CT * 16) + cout] : 0.f;
    Wp[i] = f2b(v);
}

// ---------- pack W1 (Cin=3) with 4 taps folded into K=32 (zero pad tap 27) ----------
__global__ __launch_bounds__(256) void pack_w1_kernel(const float* __restrict__ W1,
                                                      unsigned short* __restrict__ Wp) {
    int i = blockIdx.x * 256 + threadIdx.x;
    const int total = 7 * 4 * 64 * 8;
    if (i >= total) return;
    int j = i & 7;
    int l = (i >> 3) & 63;
    int t = (i >> 9) & 3;
    int kb = i >> 11;
    int tap = kb * 4 + (l >> 4);
    float v = 0.f;
    if (tap < 27 && j < 3) v = W1[(tap * 3 + j) * 64 + t * 16 + (l & 15)];
    Wp[i] = f2b(v);
}

// ---------- zero the sentinel gather row ----------
__global__ void zero_row_kernel(unsigned short* __restrict__ xb) {
    if (threadIdx.x < 64) xb[(size_t)N_FULL * 64 + threadIdx.x] = 0;
}

// ---------- conv1: MFMA, 4 taps per K=32, ONE staging phase, fused stats ----------
__global__ __launch_bounds__(256) void conv1_mfma_kernel(const float* __restrict__ feats,
                                                         const unsigned short* __restrict__ Wp,
                                                         const int* __restrict__ nbr,
                                                         unsigned short* __restrict__ Y,
                                                         float* __restrict__ sums, int R) {
    __shared__ unsigned short lw[7 * 2048];          // 28 KB: all packed W1
    __shared__ float psum[4][64], psq[4][64];
    const int tid = threadIdx.x;
    const int wave = tid >> 6;
    const int lane = tid & 63;
    const int l16 = lane & 15;
    const int lq = lane >> 4;
    const int rowbase = blockIdx.x * 128 + wave * 32;

    {
        const char* gsrc = (const char*)Wp;
        char* lbase = (char*)lw;
        #pragma unroll
        for (int c = 0; c < 7; ++c) {
            int off = (wave * 7 + c) * 1024;
            gll16(gsrc + off + lane * 16, lbase + off);
        }
    }
    int idx[7][2];
    #pragma unroll
    for (int g = 0; g < 7; ++g) {
        int tap = g * 4 + lq;
        #pragma unroll
        for (int s = 0; s < 2; ++s)
            idx[g][s] = (tap < 27) ? nbr[(size_t)tap * R + rowbase + s * 16 + l16] : -1;
    }
    __syncthreads();

    f32x4 acc[2][4];
    #pragma unroll
    for (int s = 0; s < 2; ++s)
        #pragma unroll
        for (int t = 0; t < 4; ++t)
            #pragma unroll
            for (int g = 0; g < 4; ++g) acc[s][t][g] = 0.f;
    bf16x8 zf;
    #pragma unroll
    for (int j = 0; j < 8; ++j) zf[j] = 0;

    bf16x8 af[7][2];
    #pragma unroll
    for (int g = 0; g < 7; ++g)
        #pragma unroll
        for (int s = 0; s < 2; ++s) {
            af[g][s] = zf;
            int ic = idx[g][s];
            if (ic >= 0) {
                af[g][s][0] = (short)f2b(feats[ic * 3 + 0]);
                af[g][s][1] = (short)f2b(feats[ic * 3 + 1]);
                af[g][s][2] = (short)f2b(feats[ic * 3 + 2]);
            }
        }
    #pragma unroll
    for (int g = 0; g < 7; ++g) {
        #pragma unroll
        for (int t = 0; t < 4; ++t) {
            bf16x8 bfr = *reinterpret_cast<const bf16x8*>(&lw[g * 2048 + t * 512 + lane * 8]);
            #pragma unroll
            for (int s = 0; s < 2; ++s)
                acc[s][t] = __builtin_amdgcn_mfma_f32_16x16x32_bf16(af[g][s], bfr, acc[s][t], 0, 0, 0);
        }
    }
    #pragma unroll
    for (int t = 0; t < 4; ++t) {
        float s1 = 0.f, s2 = 0.f;
        #pragma unroll
        for (int s = 0; s < 2; ++s)
            #pragma unroll
            for (int g = 0; g < 4; ++g) {
                float v = acc[s][t][g];
                s1 += v; s2 += v * v;
                Y[(size_t)(rowbase + s * 16 + lq * 4 + g) * 64 + t * 16 + l16] = f2b(v);
            }
        s1 += __shfl_xor(s1, 16); s2 += __shfl_xor(s2, 16);
        s1 += __shfl_xor(s1, 32); s2 += __shfl_xor(s2, 32);
        if (lq == 0) { psum[wave][t * 16 + l16] = s1; psq[wave][t * 16 + l16] = s2; }
    }
    __syncthreads();
    if (tid < 64) {
        float s1 = 0.f, s2 = 0.f;
        #pragma unroll
        for (int w = 0; w < 4; ++w) { s1 += psum[w][tid]; s2 += psq[w][tid]; }
        atomicAdd(&sums[tid], s1);
        atomicAdd(&sums[64 + tid], s2);
    }
}

// ---------- MFMA sparse conv: double-buffered W staging, counted vmcnt ----------
// NPT = padded taps (zero weights beyond 26), NPH = NPT/TCH must be EVEN.
template<int CT, int TCH, int NPT>
__global__ __launch_bounds__(256) void conv_mfma_kernel(const unsigned short* __restrict__ X,
                                                        const unsigned short* __restrict__ Wp,
                                                        const int* __restrict__ nbr,
                                                        unsigned short* __restrict__ Y,
                                                        float* __restrict__ sums,
                                                        int Nout, int zrow) {
    constexpr int C = CT * 16;
    constexpr int NPH = NPT / TCH;           // even
    constexpr int TAPW = CT * 1024;          // u16 per tap
    constexpr int PHW = TCH * TAPW;          // u16 per phase (16 KB both convs)
    constexpr int SCH = TCH * CT / 2;        // gll16 chunks per wave per phase
    constexpr int VM = TCH * 6;              // gathers(4*TCH) + idx(2*TCH) outstanding
    __shared__ unsigned short lw[2][PHW];
    __shared__ float psum[4][C], psq[4][C];
    const int tid = threadIdx.x;
    const int wave = tid >> 6;
    const int lane = tid & 63;
    const int l16 = lane & 15;
    const int lq = lane >> 4;
    const int rowbase = blockIdx.x * 128 + wave * 32;

    f32x4 acc[2][CT];
    #pragma unroll
    for (int s = 0; s < 2; ++s)
        #pragma unroll
        for (int t = 0; t < CT; ++t)
            #pragma unroll
            for (int g = 0; g < 4; ++g) acc[s][t][g] = 0.f;

    auto stage = [&](unsigned short* dst, int seg) {
        const char* g = (const char*)(Wp + (size_t)seg * PHW);
        char* l = (char*)dst;
        const int woff = wave * (SCH * 1024);
        #pragma unroll
        for (int c = 0; c < SCH; ++c) {
            int off = woff + c * 1024;
            gll16(g + off + lane * 16, l + off);
        }
    };
    auto gatherA = [&](bf16x8 (&af)[TCH][2][2], const int (&id)[TCH][2]) {
        #pragma unroll
        for (int t = 0; t < TCH; ++t)
            #pragma unroll
            for (int s = 0; s < 2; ++s) {
                int ic = id[t][s] < 0 ? zrow : id[t][s];
                const unsigned short* base = X + (size_t)ic * 64 + lq * 8;
                af[t][s][0] = *reinterpret_cast<const bf16x8*>(base);
                af[t][s][1] = *reinterpret_cast<const bf16x8*>(base + 32);
            }
    };
    auto loadIdx = [&](int (&id)[TCH][2], int ph2) {
        #pragma unroll
        for (int t = 0; t < TCH; ++t) {
            int tap = ph2 * TCH + t;
            if (tap > 26) tap = 26;              // padded taps have zero weights
            #pragma unroll
            for (int s = 0; s < 2; ++s)
                id[t][s] = nbr[(size_t)tap * Nout + rowbase + s * 16 + l16];
        }
    };
    auto compute = [&](const unsigned short* buf, const bf16x8 (&af)[TCH][2][2]) {
        __builtin_amdgcn_s_setprio(1);
        #pragma unroll
        for (int t = 0; t < TCH; ++t)
            #pragma unroll
            for (int q = 0; q < 2; ++q)
                #pragma unroll
                for (int tt = 0; tt < CT; ++tt) {
                    bf16x8 b = *reinterpret_cast<const bf16x8*>(
                        &buf[t * TAPW + (q * CT + tt) * 512 + lane * 8]);
                    #pragma unroll
                    for (int s = 0; s < 2; ++s)
                        acc[s][tt] = __builtin_amdgcn_mfma_f32_16x16x32_bf16(
                            af[t][s][q], b, acc[s][tt], 0, 0, 0);
                }
        __builtin_amdgcn_s_setprio(0);
    };
    auto body = [&](int ph, const unsigned short* bufc, unsigned short* bufn,
                    const bf16x8 (&afc)[TCH][2][2], bf16x8 (&afn)[TCH][2][2],
                    const int (&idu)[TCH][2], int (&idw)[TCH][2]) {
        int seg = ph + 1; if (seg > NPH - 1) seg = NPH - 1;
        stage(bufn, seg);                         // S vmem ops
        asm volatile("" ::: "memory");            // pin: stages before gathers in vmem order
        gatherA(afn, idu);                        // G vmem ops (A for phase ph+1)
        loadIdx(idw, ph + 2);                     // I vmem ops (idx for phase ph+2)
        compute(bufc, afc);                       // LDS + MFMA only
        if constexpr (VM == 6)
            asm volatile("s_waitcnt vmcnt(6)" ::: "memory");
        else if constexpr (VM == 12)
            asm volatile("s_waitcnt vmcnt(12)" ::: "memory");
        else
            asm volatile("s_waitcnt vmcnt(0)" ::: "memory");
        __builtin_amdgcn_s_barrier();
        asm volatile("" ::: "memory");
    };

    // prologue
    int id0[TCH][2], id1[TCH][2];
    bf16x8 af0[TCH][2][2], af1[TCH][2][2];
    stage((unsigned short*)lw[0], 0);
    loadIdx(id0, 0);
    gatherA(af0, id0);        // A[0]
    loadIdx(id0, 1);          // id0 <- idx[phase 1] (prev values consumed)
    __syncthreads();          // full drain once

    for (int ph = 0; ph < NPH; ph += 2) {
        body(ph,     (unsigned short*)lw[0], (unsigned short*)lw[1], af0, af1, id0, id1);
        body(ph + 1, (unsigned short*)lw[1], (unsigned short*)lw[0], af1, af0, id1, id0);
    }

    // epilogue: D layout col=lane&15, row=(lane>>4)*4+g; fused stats
    #pragma unroll
    for (int t = 0; t < CT; ++t) {
        float s1 = 0.f, s2 = 0.f;
        #pragma unroll
        for (int s = 0; s < 2; ++s)
            #pragma unroll
            for (int g = 0; g < 4; ++g) {
                float v = acc[s][t][g];
                s1 += v; s2 += v * v;
                Y[(size_t)(rowbase + s * 16 + lq * 4 + g) * C + t * 16 + l16] = f2b(v);
            }
        s1 += __shfl_xor(s1, 16); s2 += __shfl_xor(s2, 16);
        s1 += __shfl_xor(s1, 32); s2 += __shfl_xor(s2, 32);
        if (lq == 0) { psum[wave][t * 16 + l16] = s1; psq[wave][t * 16 + l16] = s2; }
    }
    __syncthreads();
    if (tid < C) {
        float s1 = 0.f, s2 = 0.f;
        #pragma unroll
        for (int w = 0; w < 4; ++w) { s1 += psum[w][tid]; s2 += psq[w][tid]; }
        atomicAdd(&sums[tid], s1);
        atomicAdd(&sums[C + tid], s2);
    }
}

// ---------- normalize + relu : bf16 in -> bf16 out ----------
template<int C>
__global__ __launch_bounds__(256) void norm_bf16_kernel(const unsigned short* __restrict__ Y,
                                                        const float* __restrict__ sums,
                                                        unsigned short* __restrict__ Xb, int R) {
    __shared__ float lmu[C], lrs[C];
    if (threadIdx.x < C) {
        float m = sums[threadIdx.x] / (float)R;
        float v = sums[C + threadIdx.x] / (float)R - m * m;
        lmu[threadIdx.x] = m;
        lrs[threadIdx.x] = rsqrtf(fmaxf(v, 0.f) + 1e-5f);
    }
    __syncthreads();
    const int total = R * C / 8;
    for (int i = blockIdx.x * 256 + threadIdx.x; i < total; i += gridDim.x * 256) {
        u16x8 v = reinterpret_cast<const u16x8*>(Y)[i];
        int cb = (i * 8) & (C - 1);
        u16x8 o;
        #pragma unroll
        for (int j = 0; j < 8; ++j) {
            float f = b2f(v[j]);
            o[j] = f2b(fmaxf((f - lmu[cb + j]) * lrs[cb + j], 0.f));
        }
        reinterpret_cast<u16x8*>(Xb)[i] = o;
    }
}

// ---------- normalize + relu : bf16 in -> f32 out (final) ----------
template<int C>
__global__ __launch_bounds__(256) void norm_f32_kernel(const unsigned short* __restrict__ Y,
                                                       const float* __restrict__ sums,
                                                       float* __restrict__ Out, int R) {
    __shared__ float lmu[C], lrs[C];
    if (threadIdx.x < C) {
        float m = sums[threadIdx.x] / (float)R;
        float v = sums[C + threadIdx.x] / (float)R - m * m;
        lmu[threadIdx.x] = m;
        lrs[threadIdx.x] = rsqrtf(fmaxf(v, 0.f) + 1e-5f);
    }
    __syncthreads();
    const int total = R * C / 8;
    for (int i = blockIdx.x * 256 + threadIdx.x; i < total; i += gridDim.x * 256) {
        u16x8 v = reinterpret_cast<const u16x8*>(Y)[i];
        int cb = (i * 8) & (C - 1);
        float4 o0, o1;
        o0.x = fmaxf((b2f(v[0]) - lmu[cb + 0]) * lrs[cb + 0], 0.f);
        o0.y = fmaxf((b2f(v[1]) - lmu[cb + 1]) * lrs[cb + 1], 0.f);
        o0.z = fmaxf((b2f(v[2]) - lmu[cb + 2]) * lrs[cb + 2], 0.f);
        o0.w = fmaxf((b2f(v[3]) - lmu[cb + 3]) * lrs[cb + 3], 0.f);
        o1.x = fmaxf((b2f(v[4]) - lmu[cb + 4]) * lrs[cb + 4], 0.f);
        o1.y = fmaxf((b2f(v[5]) - lmu[cb + 5]) * lrs[cb + 5], 0.f);
        o1.z = fmaxf((b2f(v[6]) - lmu[cb + 6]) * lrs[cb + 6], 0.f);
        o1.w = fmaxf((b2f(v[7]) - lmu[cb + 7]) * lrs[cb + 7], 0.f);
        reinterpret_cast<float4*>(Out)[i * 2] = o0;
        reinterpret_cast<float4*>(Out)[i * 2 + 1] = o1;
    }
}

// ---------- max-pool raw conv2 output, then normalize+relu -> bf16 ----------
// valid: inst_norm (rstd>0) and relu are monotone increasing -> pool/norm commute
__global__ __launch_bounds__(256) void pool_norm_kernel(const unsigned short* __restrict__ Y2,
                                                        const int* __restrict__ pmap,
                                                        const float* __restrict__ sums,
                                                        unsigned short* __restrict__ Xp,
                                                        int M, int R) {
    __shared__ float lmu[64], lrs[64];
    if (threadIdx.x < 64) {
        float m = sums[threadIdx.x] / (float)R;
        float v = sums[64 + threadIdx.x] / (float)R - m * m;
        lmu[threadIdx.x] = m;
        lrs[threadIdx.x] = rsqrtf(fmaxf(v, 0.f) + 1e-5f);
    }
    __syncthreads();
    const int lane = threadIdx.x & 63;
    const int gw = blockIdx.x * 4 + (threadIdx.x >> 6);
    const int nw = gridDim.x * 4;
    for (int m = gw; m < M; m += nw) {
        int idx[8];
        #pragma unroll
        for (int o = 0; o < 8; ++o) idx[o] = pmap[o * M + m];
        float best = -INFINITY;
        #pragma unroll
        for (int o = 0; o < 8; ++o)
            if (idx[o] >= 0) best = fmaxf(best, b2f(Y2[(size_t)idx[o] * 64 + lane]));
        Xp[(size_t)m * 64 + lane] = f2b(fmaxf((best - lmu[lane]) * lrs[lane], 0.f));
    }
}

extern "C" void kernel_launch(void* const* d_in, const int* in_sizes, int n_in,
                              void* d_out, int out_size, void* d_ws, size_t ws_size,
                              hipStream_t stream) {
    const float* feats = (const float*)d_in[0];
    const float* W1 = (const float*)d_in[1];
    const float* W2 = (const float*)d_in[2];
    const float* W3 = (const float*)d_in[3];
    const int* nbr1 = (const int*)d_in[4];
    const int* pmap = (const int*)d_in[5];
    const int* nbr2 = (const int*)d_in[6];
    float* out = (float*)d_out;

    const int N = N_FULL, M = M_POOL;
    char* ws = (char*)d_ws;
    unsigned short* yb = (unsigned short*)ws;              // bf16 N*64 (y1,y2,y3)
    unsigned short* xb = yb + (size_t)N * 64;              // bf16 (N+1)*64 (x1 / pooled x + zero row)
    unsigned short* w1p = xb + (size_t)(N + 1) * 64;       // 7*2048
    unsigned short* w2p = w1p + 7 * 2048;                  // 28 taps * 4096
    unsigned short* w3p = w2p + 28 * 4096;                 // 28 taps * 8192
    float* sums = (float*)(w3p + 28 * 8192);
    float* sums1 = sums;
    float* sums2 = sums + 128;
    float* sums3 = sums + 256;

    hipMemsetAsync(sums, 0, 512 * sizeof(float), stream);
    zero_row_kernel<<<1, 64, 0, stream>>>(xb);
    pack_w1_kernel<<<(7 * 2048 + 255) / 256, 256, 0, stream>>>(W1, w1p);
    pack_w_kernel<4, 28><<<(28 * 4096 + 255) / 256, 256, 0, stream>>>(W2, w2p);
    pack_w_kernel<8, 28><<<(28 * 8192 + 255) / 256, 256, 0, stream>>>(W3, w3p);

    conv1_mfma_kernel<<<N / 128, 256, 0, stream>>>(feats, w1p, nbr1, yb, sums1, N);
    norm_bf16_kernel<64><<<2048, 256, 0, stream>>>(yb, sums1, xb, N);

    conv_mfma_kernel<4, 2, 28><<<N / 128, 256, 0, stream>>>(xb, w2p, nbr1, yb, sums2, N, N);
    pool_norm_kernel<<<2048, 256, 0, stream>>>(yb, pmap, sums2, xb, M, N);

    conv_mfma_kernel<8, 1, 28><<<M / 128, 256, 0, stream>>>(xb, w3p, nbr2, yb, sums3, M, N);
    norm_f32_kernel<128><<<2048, 256, 0, stream>>>(yb, sums3, out, M);
}

// Round 6
// 412.630 us; speedup vs baseline: 1.0018x; 1.0018x over previous
//
#include <hip/hip_runtime.h>
#include <hip/hip_bf16.h>

#define N_FULL 262144
#define M_POOL 131072

typedef __attribute__((ext_vector_type(4))) float f32x4;
typedef __attribute__((ext_vector_type(8))) short bf16x8;
typedef __attribute__((ext_vector_type(8))) unsigned short u16x8;

static __device__ __forceinline__ unsigned short f2b(float f) {
    __hip_bfloat16 b = __float2bfloat16(f);
    return *reinterpret_cast<unsigned short*>(&b);
}
static __device__ __forceinline__ float b2f(unsigned short u) {
    unsigned int x = ((unsigned int)u) << 16;
    return __uint_as_float(x);
}

// async global->LDS, 16B per lane; LDS dest is wave-uniform base (HW adds lane*16)
static __device__ __forceinline__ void gll16(const void* g, void* l) {
    __builtin_amdgcn_global_load_lds(
        (const __attribute__((address_space(1))) void*)g,
        (__attribute__((address_space(3))) void*)l, 16, 0, 0);
}

// ---------- pack W2/W3 into MFMA B-fragment order, zero-padded to NPT taps ----------
// Wp[k][q][t][lane][j] = W[k][q*32 + (lane>>4)*8 + j][t*16 + (lane&15)], 0 for k>=27
template<int CT, int NPT>
__global__ __launch_bounds__(256) void pack_w_kernel(const float* __restrict__ W,
                                                     unsigned short* __restrict__ Wp) {
    int i = blockIdx.x * 256 + threadIdx.x;
    const int total = NPT * 2 * CT * 64 * 8;
    if (i >= total) return;
    int j = i & 7;
    int l = (i >> 3) & 63;
    int t = (i >> 9) % CT;
    int q = (i / (512 * CT)) & 1;
    int k = i / (1024 * CT);
    int cin = q * 32 + (l >> 4) * 8 + j;
    int cout = t * 16 + (l & 15);
    float v = (k < 27) ? W[(k * 64 + cin) * (CT * 16) + cout] : 0.f;
    Wp[i] = f2b(v);
}

// ---------- pack W1 (Cin=3) with 4 taps folded into K=32; 8 groups (pad) ----------
__global__ __launch_bounds__(256) void pack_w1_kernel(const float* __restrict__ W1,
                                                      unsigned short* __restrict__ Wp) {
    int i = blockIdx.x * 256 + threadIdx.x;
    const int total = 8 * 4 * 64 * 8;
    if (i >= total) return;
    int j = i & 7;
    int l = (i >> 3) & 63;
    int t = (i >> 9) & 3;
    int kb = i >> 11;
    int tap = kb * 4 + (l >> 4);
    float v = 0.f;
    if (tap < 27 && j < 3) v = W1[(tap * 3 + j) * 64 + t * 16 + (l & 15)];
    Wp[i] = f2b(v);
}

// ---------- pack feats -> bf16x4 rows (row N = zeros sentinel) ----------
__global__ __launch_bounds__(256) void pack_feats_kernel(const float* __restrict__ feats,
                                                         unsigned short* __restrict__ fp, int N) {
    int i = blockIdx.x * 256 + threadIdx.x;
    if (i > N) return;
    ushort4 o;
    if (i < N) {
        o.x = f2b(feats[(size_t)i * 3 + 0]);
        o.y = f2b(feats[(size_t)i * 3 + 1]);
        o.z = f2b(feats[(size_t)i * 3 + 2]);
        o.w = 0;
    } else { o.x = o.y = o.z = o.w = 0; }
    reinterpret_cast<ushort4*>(fp)[i] = o;
}

// ---------- zero the sentinel gather row of xb ----------
__global__ void zero_row_kernel(unsigned short* __restrict__ xb) {
    if (threadIdx.x < 64) xb[(size_t)N_FULL * 64 + threadIdx.x] = 0;
}

// ---------- conv1: MFMA, 4 taps per K=32, ONE staging phase, 8 waves ----------
__global__ __launch_bounds__(512) void conv1_mfma_kernel(const unsigned short* __restrict__ fp,
                                                         const unsigned short* __restrict__ Wp,
                                                         const int* __restrict__ nbr,
                                                         unsigned short* __restrict__ Y,
                                                         float* __restrict__ sums, int R) {
    __shared__ unsigned short lw[8 * 2048];          // 32 KB (group 7 = zeros)
    __shared__ float psum[8][64], psq[8][64];
    const int tid = threadIdx.x;
    const int wave = tid >> 6;
    const int lane = tid & 63;
    const int l16 = lane & 15;
    const int lq = lane >> 4;
    const int rowbase = blockIdx.x * 256 + wave * 32;
    const int zrow = R;

    {   // stage all 32 KB: 32 chunks of 1 KB, 4 per wave
        const char* gsrc = (const char*)Wp;
        char* lbase = (char*)lw;
        #pragma unroll
        for (int c = 0; c < 4; ++c) {
            int off = (wave * 4 + c) * 1024;
            gll16(gsrc + off + lane * 16, lbase + off);
        }
    }
    // all idx loads (tap = g*4+lq, clamped; clamped slots hit zero weights)
    int idx[7][2];
    #pragma unroll
    for (int g = 0; g < 7; ++g) {
        int tap = g * 4 + lq; if (tap > 26) tap = 26;
        #pragma unroll
        for (int s = 0; s < 2; ++s) {
            int v = nbr[(size_t)tap * R + rowbase + s * 16 + l16];
            idx[g][s] = v < 0 ? zrow : v;
        }
    }
    // gathers: one 8B load per row
    bf16x8 af[7][2];
    #pragma unroll
    for (int g = 0; g < 7; ++g)
        #pragma unroll
        for (int s = 0; s < 2; ++s) {
            short4 v = *reinterpret_cast<const short4*>(fp + (size_t)idx[g][s] * 4);
            af[g][s][0] = v.x; af[g][s][1] = v.y; af[g][s][2] = v.z; af[g][s][3] = v.w;
            af[g][s][4] = 0; af[g][s][5] = 0; af[g][s][6] = 0; af[g][s][7] = 0;
        }
    __syncthreads();   // drains staging + gathers

    f32x4 acc[2][4];
    #pragma unroll
    for (int s = 0; s < 2; ++s)
        #pragma unroll
        for (int t = 0; t < 4; ++t)
            #pragma unroll
            for (int g = 0; g < 4; ++g) acc[s][t][g] = 0.f;

    #pragma unroll
    for (int g = 0; g < 7; ++g) {
        #pragma unroll
        for (int t = 0; t < 4; ++t) {
            bf16x8 bfr = *reinterpret_cast<const bf16x8*>(&lw[g * 2048 + t * 512 + lane * 8]);
            #pragma unroll
            for (int s = 0; s < 2; ++s)
                acc[s][t] = __builtin_amdgcn_mfma_f32_16x16x32_bf16(af[g][s], bfr, acc[s][t], 0, 0, 0);
        }
    }
    #pragma unroll
    for (int t = 0; t < 4; ++t) {
        float s1 = 0.f, s2 = 0.f;
        #pragma unroll
        for (int s = 0; s < 2; ++s)
            #pragma unroll
            for (int g = 0; g < 4; ++g) {
                float v = acc[s][t][g];
                s1 += v; s2 += v * v;
                Y[(size_t)(rowbase + s * 16 + lq * 4 + g) * 64 + t * 16 + l16] = f2b(v);
            }
        s1 += __shfl_xor(s1, 16); s2 += __shfl_xor(s2, 16);
        s1 += __shfl_xor(s1, 32); s2 += __shfl_xor(s2, 32);
        if (lq == 0) { psum[wave][t * 16 + l16] = s1; psq[wave][t * 16 + l16] = s2; }
    }
    __syncthreads();
    if (tid < 64) {
        float s1 = 0.f, s2 = 0.f;
        #pragma unroll
        for (int w = 0; w < 8; ++w) { s1 += psum[w][tid]; s2 += psq[w][tid]; }
        atomicAdd(&sums[tid], s1);
        atomicAdd(&sums[64 + tid], s2);
    }
}

// ---------- MFMA sparse conv: Cin=64, Cout=CT*16, 8 waves, TCH taps/phase ----------
template<int CT, int TCH, int NPT>
__global__ __launch_bounds__(512) void conv_mfma_kernel(const unsigned short* __restrict__ X,
                                                        const unsigned short* __restrict__ Wp,
                                                        const int* __restrict__ nbr,
                                                        unsigned short* __restrict__ Y,
                                                        float* __restrict__ sums,
                                                        int Nout, int zrow) {
    constexpr int C = CT * 16;
    constexpr int NPH = NPT / TCH;
    constexpr int TAPW = CT * 1024;              // u16 per tap
    constexpr int PHW = TCH * TAPW;              // u16 per phase
    constexpr int SCH = TCH * CT / 4;            // 1KB chunks per wave (8 waves)
    __shared__ unsigned short lw[PHW];
    __shared__ float psum[8][C], psq[8][C];
    const int tid = threadIdx.x;
    const int wave = tid >> 6;
    const int lane = tid & 63;
    const int l16 = lane & 15;
    const int lq = lane >> 4;
    const int rowbase = blockIdx.x * 256 + wave * 32;

    f32x4 acc[2][CT];
    #pragma unroll
    for (int s = 0; s < 2; ++s)
        #pragma unroll
        for (int t = 0; t < CT; ++t)
            #pragma unroll
            for (int g = 0; g < 4; ++g) acc[s][t][g] = 0.f;

    // prolog: idx for phase 0
    int idxp[TCH][2];
    #pragma unroll
    for (int t = 0; t < TCH; ++t)
        #pragma unroll
        for (int s = 0; s < 2; ++s) {
            int v = nbr[(size_t)t * Nout + rowbase + s * 16 + l16];
            idxp[t][s] = v < 0 ? zrow : v;
        }

    for (int ph = 0; ph < NPH; ++ph) {
        if (ph) __syncthreads();   // lw overwrite guard (no outstanding vmem -> cheap)
        // stage TCH taps of B
        {
            const char* gseg = (const char*)(Wp + (size_t)ph * PHW);
            char* lbase = (char*)lw;
            const int woff = wave * (SCH * 1024);
            #pragma unroll
            for (int c = 0; c < SCH; ++c) {
                int off = woff + c * 1024;
                gll16(gseg + off + lane * 16, lbase + off);
            }
        }
        // gather this phase's A fragments (branchless via sentinel row)
        bf16x8 af[TCH][2][2];
        #pragma unroll
        for (int t = 0; t < TCH; ++t)
            #pragma unroll
            for (int s = 0; s < 2; ++s) {
                const unsigned short* base = X + (size_t)idxp[t][s] * 64 + lq * 8;
                af[t][s][0] = *reinterpret_cast<const bf16x8*>(base);
                af[t][s][1] = *reinterpret_cast<const bf16x8*>(base + 32);
            }
        // issue next phase's idx loads
        int idxn[TCH][2];
        #pragma unroll
        for (int t = 0; t < TCH; ++t) {
            int tap = (ph + 1) * TCH + t; if (tap > 26) tap = 26;  // padded taps: zero W
            #pragma unroll
            for (int s = 0; s < 2; ++s) {
                int v = nbr[(size_t)tap * Nout + rowbase + s * 16 + l16];
                idxn[t][s] = v < 0 ? zrow : v;
            }
        }
        __syncthreads();   // one wide drain: staging + gathers + idx
        // compute TCH taps (LDS + MFMA only)
        #pragma unroll
        for (int t = 0; t < TCH; ++t)
            #pragma unroll
            for (int q = 0; q < 2; ++q)
                #pragma unroll
                for (int tt = 0; tt < CT; ++tt) {
                    bf16x8 bfr = *reinterpret_cast<const bf16x8*>(
                        &lw[t * TAPW + (q * CT + tt) * 512 + lane * 8]);
                    #pragma unroll
                    for (int s = 0; s < 2; ++s)
                        acc[s][tt] = __builtin_amdgcn_mfma_f32_16x16x32_bf16(
                            af[t][s][q], bfr, acc[s][tt], 0, 0, 0);
                }
        #pragma unroll
        for (int t = 0; t < TCH; ++t)
            #pragma unroll
            for (int s = 0; s < 2; ++s) idxp[t][s] = idxn[t][s];
    }
    // epilogue: D layout col=lane&15, row=(lane>>4)*4+g; fused stats
    #pragma unroll
    for (int t = 0; t < CT; ++t) {
        float s1 = 0.f, s2 = 0.f;
        #pragma unroll
        for (int s = 0; s < 2; ++s)
            #pragma unroll
            for (int g = 0; g < 4; ++g) {
                float v = acc[s][t][g];
                s1 += v; s2 += v * v;
                Y[(size_t)(rowbase + s * 16 + lq * 4 + g) * C + t * 16 + l16] = f2b(v);
            }
        s1 += __shfl_xor(s1, 16); s2 += __shfl_xor(s2, 16);
        s1 += __shfl_xor(s1, 32); s2 += __shfl_xor(s2, 32);
        if (lq == 0) { psum[wave][t * 16 + l16] = s1; psq[wave][t * 16 + l16] = s2; }
    }
    __syncthreads();
    if (tid < C) {
        float s1 = 0.f, s2 = 0.f;
        #pragma unroll
        for (int w = 0; w < 8; ++w) { s1 += psum[w][tid]; s2 += psq[w][tid]; }
        atomicAdd(&sums[tid], s1);
        atomicAdd(&sums[C + tid], s2);
    }
}

// ---------- normalize + relu : bf16 in -> bf16 out ----------
template<int C>
__global__ __launch_bounds__(256) void norm_bf16_kernel(const unsigned short* __restrict__ Y,
                                                        const float* __restrict__ sums,
                                                        unsigned short* __restrict__ Xb, int R) {
    __shared__ float lmu[C], lrs[C];
    if (threadIdx.x < C) {
        float m = sums[threadIdx.x] / (float)R;
        float v = sums[C + threadIdx.x] / (float)R - m * m;
        lmu[threadIdx.x] = m;
        lrs[threadIdx.x] = rsqrtf(fmaxf(v, 0.f) + 1e-5f);
    }
    __syncthreads();
    const int total = R * C / 8;
    for (int i = blockIdx.x * 256 + threadIdx.x; i < total; i += gridDim.x * 256) {
        u16x8 v = reinterpret_cast<const u16x8*>(Y)[i];
        int cb = (i * 8) & (C - 1);
        u16x8 o;
        #pragma unroll
        for (int j = 0; j < 8; ++j) {
            float f = b2f(v[j]);
            o[j] = f2b(fmaxf((f - lmu[cb + j]) * lrs[cb + j], 0.f));
        }
        reinterpret_cast<u16x8*>(Xb)[i] = o;
    }
}

// ---------- normalize + relu : bf16 in -> f32 out (final) ----------
template<int C>
__global__ __launch_bounds__(256) void norm_f32_kernel(const unsigned short* __restrict__ Y,
                                                       const float* __restrict__ sums,
                                                       float* __restrict__ Out, int R) {
    __shared__ float lmu[C], lrs[C];
    if (threadIdx.x < C) {
        float m = sums[threadIdx.x] / (float)R;
        float v = sums[C + threadIdx.x] / (float)R - m * m;
        lmu[threadIdx.x] = m;
        lrs[threadIdx.x] = rsqrtf(fmaxf(v, 0.f) + 1e-5f);
    }
    __syncthreads();
    const int total = R * C / 8;
    for (int i = blockIdx.x * 256 + threadIdx.x; i < total; i += gridDim.x * 256) {
        u16x8 v = reinterpret_cast<const u16x8*>(Y)[i];
        int cb = (i * 8) & (C - 1);
        float4 o0, o1;
        o0.x = fmaxf((b2f(v[0]) - lmu[cb + 0]) * lrs[cb + 0], 0.f);
        o0.y = fmaxf((b2f(v[1]) - lmu[cb + 1]) * lrs[cb + 1], 0.f);
        o0.z = fmaxf((b2f(v[2]) - lmu[cb + 2]) * lrs[cb + 2], 0.f);
        o0.w = fmaxf((b2f(v[3]) - lmu[cb + 3]) * lrs[cb + 3], 0.f);
        o1.x = fmaxf((b2f(v[4]) - lmu[cb + 4]) * lrs[cb + 4], 0.f);
        o1.y = fmaxf((b2f(v[5]) - lmu[cb + 5]) * lrs[cb + 5], 0.f);
        o1.z = fmaxf((b2f(v[6]) - lmu[cb + 6]) * lrs[cb + 6], 0.f);
        o1.w = fmaxf((b2f(v[7]) - lmu[cb + 7]) * lrs[cb + 7], 0.f);
        reinterpret_cast<float4*>(Out)[i * 2] = o0;
        reinterpret_cast<float4*>(Out)[i * 2 + 1] = o1;
    }
}

// ---------- max-pool raw conv2 output, then normalize+relu -> bf16 ----------
// valid: inst_norm (rstd>0) and relu are monotone increasing -> pool/norm commute
__global__ __launch_bounds__(256) void pool_norm_kernel(const unsigned short* __restrict__ Y2,
                                                        const int* __restrict__ pmap,
                                                        const float* __restrict__ sums,
                                                        unsigned short* __restrict__ Xp,
                                                        int M, int R) {
    __shared__ float lmu[64], lrs[64];
    if (threadIdx.x < 64) {
        float m = sums[threadIdx.x] / (float)R;
        float v = sums[64 + threadIdx.x] / (float)R - m * m;
        lmu[threadIdx.x] = m;
        lrs[threadIdx.x] = rsqrtf(fmaxf(v, 0.f) + 1e-5f);
    }
    __syncthreads();
    const int lane = threadIdx.x & 63;
    const int gw = blockIdx.x * 4 + (threadIdx.x >> 6);
    const int nw = gridDim.x * 4;
    for (int m = gw; m < M; m += nw) {
        int idx[8];
        #pragma unroll
        for (int o = 0; o < 8; ++o) idx[o] = pmap[o * M + m];
        float best = -INFINITY;
        #pragma unroll
        for (int o = 0; o < 8; ++o)
            if (idx[o] >= 0) best = fmaxf(best, b2f(Y2[(size_t)idx[o] * 64 + lane]));
        Xp[(size_t)m * 64 + lane] = f2b(fmaxf((best - lmu[lane]) * lrs[lane], 0.f));
    }
}

extern "C" void kernel_launch(void* const* d_in, const int* in_sizes, int n_in,
                              void* d_out, int out_size, void* d_ws, size_t ws_size,
                              hipStream_t stream) {
    const float* feats = (const float*)d_in[0];
    const float* W1 = (const float*)d_in[1];
    const float* W2 = (const float*)d_in[2];
    const float* W3 = (const float*)d_in[3];
    const int* nbr1 = (const int*)d_in[4];
    const int* pmap = (const int*)d_in[5];
    const int* nbr2 = (const int*)d_in[6];
    float* out = (float*)d_out;

    const int N = N_FULL, M = M_POOL;
    char* ws = (char*)d_ws;
    unsigned short* yb = (unsigned short*)ws;              // bf16 N*64 (y1,y2,y3)
    unsigned short* xb = yb + (size_t)N * 64;              // bf16 (N+1)*64 + zero row
    unsigned short* fpk = xb + (size_t)(N + 1) * 64;       // bf16 (N+1)*4 packed feats
    unsigned short* w1p = fpk + (size_t)(N + 1) * 4;       // 8*2048
    unsigned short* w2p = w1p + 8 * 2048;                  // 30 taps * 4096
    unsigned short* w3p = w2p + 30 * 4096;                 // 27 taps * 8192
    float* sums = (float*)(w3p + 27 * 8192);
    float* sums1 = sums;
    float* sums2 = sums + 128;
    float* sums3 = sums + 256;

    hipMemsetAsync(sums, 0, 512 * sizeof(float), stream);
    zero_row_kernel<<<1, 64, 0, stream>>>(xb);
    pack_feats_kernel<<<(N + 256) / 256, 256, 0, stream>>>(feats, fpk, N);
    pack_w1_kernel<<<(8 * 2048 + 255) / 256, 256, 0, stream>>>(W1, w1p);
    pack_w_kernel<4, 30><<<(30 * 4096 + 255) / 256, 256, 0, stream>>>(W2, w2p);
    pack_w_kernel<8, 27><<<(27 * 8192 + 255) / 256, 256, 0, stream>>>(W3, w3p);

    conv1_mfma_kernel<<<N / 256, 512, 0, stream>>>(fpk, w1p, nbr1, yb, sums1, N);
    norm_bf16_kernel<64><<<2048, 256, 0, stream>>>(yb, sums1, xb, N);

    conv_mfma_kernel<4, 6, 30><<<N / 256, 512, 0, stream>>>(xb, w2p, nbr1, yb, sums2, N, N);
    pool_norm_kernel<<<2048, 256, 0, stream>>>(yb, pmap, sums2, xb, M, N);

    conv_mfma_kernel<8, 3, 27><<<M / 256, 512, 0, stream>>>(xb, w3p, nbr2, yb, sums3, M, N);
    norm_f32_kernel<128><<<2048, 256, 0, stream>>>(yb, sums3, out, M);
}